// Round 15
// baseline (236.390 us; speedup 1.0000x reference)
//
#include <hip/hip_runtime.h>

// ContrastiveLoss: B=8192, D=128, T=0.1, SINGLE_POS=False.
// Classes c = 2*tt + tp in {0..3}; pos class = c^1, neg class = c^2.
// Rows counting-sorted by class; each wave visits only the <=2 relevant
// column segments. B staged per 64-row panel via global_load_lds, double
// buffer, rotation swizzle. 8 waves x 16 rows (512-thr blocks) fits the
// empirically-immovable 64-VGPR clamp (r13: matched best, no spill).
// THIS ROUND: finalize folded into sim via per-i-block arrival counters —
// the 16th j-slice block finishing an i-block reduces that i-block's 128
// rows (~2us, overlapped). Saves one dispatch boundary. Fence/atomic-load
// pattern verified in r2 (absmax 0.0).

#define NB 8192
#define ND 128
#define NIB 64          // i-blocks (128 rows each)
#define JS 16           // j-slices -> grid 64*16 = 1024 blocks (4/CU @ 32KB LDS)
#define NH 8            // classify histogram groups (1024 rows each)
#define TEMP_INV 10.0f
#define LOG2E 1.4426950408889634f
#define EXPK (TEMP_INV * LOG2E)

typedef __attribute__((ext_vector_type(8))) short short8;
typedef __attribute__((ext_vector_type(4))) float f32x4;

// ws layout (bytes)
#define OFF_G    0                         // 8192*128 bf16 = 2 MB
#define OFF_CLS  (NB * ND * 2)             // sorted classes u8[8192]
#define OFF_CNT  (OFF_CLS + NB)            // per-h class hist int[NH*4]
#define OFF_CTR  (OFF_CNT + 128)           // per-i-block arrival ctr int[64]
#define OFF_EPP  (OFF_CTR + 256)           // JS*8192 f32 partials
#define OFF_ENP  (OFF_EPP + NB * 4 * JS)
#define OFF_LSP  (OFF_ENP + NB * 4 * JS)
// aliased into the Ep partial region (dead before sim overwrites every slot):
#define OFF_CO   OFF_EPP                   // original classes u8[8192]
#define OFF_RL   (OFF_EPP + NB)            // local rank in (h,class) u16[8192]

__device__ __forceinline__ unsigned short f2bf(float x) {
    unsigned int u = __float_as_uint(x);
    unsigned int r = (u + 0x7FFFu + ((u >> 16) & 1u)) >> 16;  // RNE
    return (unsigned short)r;
}

__device__ __forceinline__ float fast_exp2(float x) {
#if __has_builtin(__builtin_amdgcn_exp2f)
    return __builtin_amdgcn_exp2f(x);
#else
    return exp2f(x);
#endif
}

typedef const __attribute__((address_space(1))) void gas_void;
typedef __attribute__((address_space(3))) void las_void;
__device__ __forceinline__ void gload_lds16(const void* g, void* s) {
    // width-16 global->LDS DMA; LDS dest = uniform base + lane*16 (HW rule)
    __builtin_amdgcn_global_load_lds((gas_void*)g, (las_void*)s, 16, 0, 0);
}

// 8 blocks x 1024 (1 row/thread): classes, per-(h,class) hist + local ranks.
// Also zeroes out and the 64 per-i-block arrival counters.
__global__ __launch_bounds__(1024) void classify_kernel(
    const int* __restrict__ dix, const int* __restrict__ tt, const int* __restrict__ tp,
    unsigned char* __restrict__ clsO, unsigned short* __restrict__ rlocal,
    int* __restrict__ cntP, int* __restrict__ ctr, float* __restrict__ out)
{
    __shared__ int lh[4];
    const int h = blockIdx.x, tid = threadIdx.x;
    if (tid < 4) lh[tid] = 0;
    __syncthreads();
    const int row = h * 1024 + tid;
    const int ix  = dix[row];
    const int c   = ((tt[ix] & 1) << 1) | (tp[ix] & 1);
    clsO[row] = (unsigned char)c;
    rlocal[row] = (unsigned short)atomicAdd(&lh[c], 1);
    if (tid < 8) ctr[h * 8 + tid] = 0;
    if (h == 0 && tid == 0) *out = 0.0f;
    __syncthreads();
    if (tid < 4) cntP[h * 4 + tid] = lh[tid];
}

// 2048 blocks x 256 (wave per row): normalize row, scatter to sorted slot.
__global__ __launch_bounds__(256) void normscatter_kernel(
    const float* __restrict__ F, const unsigned char* __restrict__ clsO,
    const unsigned short* __restrict__ rlocal, const int* __restrict__ cntP,
    unsigned short* __restrict__ G, unsigned char* __restrict__ clsS)
{
    const int row  = blockIdx.x * 4 + (threadIdx.x >> 6);
    const int lane = threadIdx.x & 63;
    const int c = clsO[row];
    const int h = row >> 10;                 // 1024 rows per hist group
    int base = (int)rlocal[row];
    #pragma unroll
    for (int cc = 0; cc < 3; ++cc)           // classes below c (wave-uniform)
        if (cc < c) {
            #pragma unroll
            for (int hh = 0; hh < NH; ++hh) base += cntP[hh * 4 + cc];
        }
    #pragma unroll
    for (int hh = 0; hh < NH - 1; ++hh)      // earlier hist groups, same class
        if (hh < h) base += cntP[hh * 4 + c];

    const float2 v = *(const float2*)(F + row * ND + lane * 2);
    float ss = v.x * v.x + v.y * v.y;
    #pragma unroll
    for (int m = 1; m < 64; m <<= 1) ss += __shfl_xor(ss, m, 64);
    const float inv = rsqrtf(fmaxf(ss, 1e-24f));
    ushort2 st; st.x = f2bf(v.x * inv); st.y = f2bf(v.y * inv);
    *(ushort2*)(G + base * ND + lane * 2) = st;
    if (lane == 0) clsS[base] = (unsigned char)c;
}

// Stage one 64-row panel with 8 waves: wave wu stages rows wu*8..wu*8+7
// (2 gload_lds per wave). Lane l -> row pr = wu*8 + j*4 + (l>>4); slot l&15
// holds global chunk (slot - pr) & 15 (rotation; read applies same perm).
__device__ __forceinline__ void stage_panel(
    const unsigned short* __restrict__ G, unsigned short* Blds,
    int rbase, int wu, int lrow4, int lpos)
{
    #pragma unroll
    for (int j = 0; j < 2; ++j) {
        const int pr = wu * 8 + j * 4 + lrow4;
        int rowG = rbase + pr;
        rowG = (rowG < NB - 1) ? rowG : (NB - 1);   // clamp (masked in compute)
        const int chunk = (lpos - pr) & 15;
        gload_lds16(G + rowG * ND + chunk * 8, Blds + (wu * 8 + j * 4) * ND);
    }
}

// MODE: 0 = stage-only (inactive wave), 1 = POS (Ep,Ls), 2 = NEG (En),
// 3 = weighted both (straddling waves only — rare after sorting).
// Double-buffered 2-phase: stage(p+1) issued BEFORE compute(p).
template<int MODE>
__device__ __forceinline__ void seg_panels(
    const unsigned short* __restrict__ G, unsigned short* Blds0,
    unsigned short* Blds1, const short8 (&A)[4],
    float (&Ep)[4], float (&En)[4], float (&Ls)[4],
    const float (&wp)[4], const float (&wn)[4],
    int cs, int ce, int p0, int p1, int wu, int lane)
{
    const int lrow4 = lane >> 4, lpos = lane & 15;
    const int q = lane >> 4, l16 = lane & 15;

    stage_panel(G, Blds0, cs + p0 * 64, wu, lrow4, lpos);
    __syncthreads();                       // panel p0 ready
    #pragma unroll 1
    for (int p = p0; p < p1; ++p) {
        const int cur = (p - p0) & 1;
        unsigned short* bufC = cur ? Blds1 : Blds0;
        if (p + 1 < p1)                    // prefetch next panel into other buf
            stage_panel(G, cur ? Blds0 : Blds1, cs + (p + 1) * 64, wu, lrow4, lpos);
        if (MODE != 0) {
            #pragma unroll
            for (int st = 0; st < 4; ++st) {
                const int j0 = cs + p * 64 + st * 16;
                if (j0 >= ce) break;       // wave-uniform tail cutoff
                short8 Bf[4];
                #pragma unroll
                for (int c = 0; c < 4; ++c) {
                    const int slot = (c * 4 + q + l16) & 15;    // rotation
                    Bf[c] = *(const short8*)&bufC[(st * 16 + l16) * ND + slot * 8];
                }
                f32x4 acc = {0.f, 0.f, 0.f, 0.f};
                #pragma unroll
                for (int c = 0; c < 4; ++c)
                    acc = __builtin_amdgcn_mfma_f32_16x16x32_bf16(A[c], Bf[c], acc, 0, 0, 0);
                if (j0 + 16 <= ce) {       // full subtile
                    #pragma unroll
                    for (int r = 0; r < 4; ++r) {
                        const float sv = acc[r];
                        const float e  = fast_exp2(sv * EXPK);
                        if (MODE == 1)      { Ep[r] += e; Ls[r] += sv; }
                        else if (MODE == 2) { En[r] += e; }
                        else {
                            Ep[r] = fmaf(wp[r], e,  Ep[r]);
                            Ls[r] = fmaf(wp[r], sv, Ls[r]);
                            En[r] = fmaf(wn[r], e,  En[r]);
                        }
                    }
                } else {                   // masked tail subtile
                    const float vm = ((j0 + l16) < ce) ? 1.f : 0.f;
                    #pragma unroll
                    for (int r = 0; r < 4; ++r) {
                        const float sv = acc[r] * vm;
                        const float e  = fast_exp2(sv * EXPK) * vm;
                        if (MODE == 1)      { Ep[r] += e; Ls[r] += sv; }
                        else if (MODE == 2) { En[r] += e; }
                        else {
                            Ep[r] = fmaf(wp[r], e,  Ep[r]);
                            Ls[r] = fmaf(wp[r], sv, Ls[r]);
                            En[r] = fmaf(wn[r], e,  En[r]);
                        }
                    }
                }
            }
        }
        __syncthreads();   // drains prefetch vmcnt + fences reads of bufC
    }
}

// Grid 64 i-blocks x 16 j-slices = 1024 blocks of 512 threads (8 waves).
// The 16th block finishing an i-block reduces that i-block's 128 rows.
__global__ __launch_bounds__(512) void sim_kernel(
    const unsigned short* __restrict__ G, const unsigned char* __restrict__ clsS,
    const int* __restrict__ cntP, int* __restrict__ ctr,
    float* __restrict__ EpP, float* __restrict__ EnP, float* __restrict__ LsP,
    float* __restrict__ out)
{
    __shared__ unsigned short Blds[2][64 * 128];   // 2 x 16 KB

    const int ib = blockIdx.x & (NIB - 1);
    const int jb = blockIdx.x >> 6;          // 0..JS-1
    const int wave = threadIdx.x >> 6, lane = threadIdx.x & 63;
    const int q = lane >> 4, l16 = lane & 15;
    const int ri = ib * 128 + wave * 16;     // this wave's 16 rows
    const int wu = __builtin_amdgcn_readfirstlane(wave);

    short8 A[4];
    #pragma unroll
    for (int c = 0; c < 4; ++c)
        A[c] = *(const short8*)(G + (ri + l16) * ND + c * 32 + q * 8);

    // this lane's 4 output-row classes (C/D row = 4q + r)
    const unsigned int rc = *(const unsigned int*)(clsS + ri + 4 * q);
    const int wF = clsS[ri], wL = clsS[ri + 15];              // wave class range
    const int bF = clsS[ib * 128], bL = clsS[ib * 128 + 127]; // block class range

    float Ep[4], En[4], Ls[4];
    #pragma unroll
    for (int i = 0; i < 4; ++i) { Ep[i] = 0.f; En[i] = 0.f; Ls[i] = 0.f; }
    float wp[4], wn[4];   // written only on the (rare) straddle path

    int cs = 0;
    #pragma unroll 1
    for (int s = 0; s < 4; ++s) {
        int len = 0;
        #pragma unroll
        for (int h = 0; h < NH; ++h) len += cntP[h * 4 + s];
        const int ce = cs + len;
        const int s1 = s ^ 1, s2 = s ^ 2;
        const bool aPb = (s1 >= bF) && (s1 <= bL);   // block-uniform activity
        const bool aNb = (s2 >= bF) && (s2 <= bL);
        if (aPb || aNb) {
            const int np = (len + 63) >> 6;          // 64-row panels
            const int p0 = (jb * np) >> 4;           // this block's panel range
            const int p1 = ((jb + 1) * np) >> 4;
            if (p0 < p1) {
                if (wF == wL) {                       // pure-class wave (common)
                    if (s1 == wF)
                        seg_panels<1>(G, Blds[0], Blds[1], A, Ep, En, Ls, wp, wn, cs, ce, p0, p1, wu, lane);
                    else if (s2 == wF)
                        seg_panels<2>(G, Blds[0], Blds[1], A, Ep, En, Ls, wp, wn, cs, ce, p0, p1, wu, lane);
                    else
                        seg_panels<0>(G, Blds[0], Blds[1], A, Ep, En, Ls, wp, wn, cs, ce, p0, p1, wu, lane);
                } else {                              // straddling wave (rare)
                    #pragma unroll
                    for (int r = 0; r < 4; ++r) {
                        const int cr = (rc >> (8 * r)) & 0xff;
                        wp[r] = (cr == s1) ? 1.f : 0.f;
                        wn[r] = (cr == s2) ? 1.f : 0.f;
                    }
                    seg_panels<3>(G, Blds[0], Blds[1], A, Ep, En, Ls, wp, wn, cs, ce, p0, p1, wu, lane);
                }
            }
        }
        cs = ce;
    }

    // reduce across the 16 column-lanes
    #pragma unroll
    for (int m = 1; m < 16; m <<= 1)
        #pragma unroll
        for (int i = 0; i < 4; ++i) {
            Ep[i] += __shfl_xor(Ep[i], m, 64);
            En[i] += __shfl_xor(En[i], m, 64);
            Ls[i] += __shfl_xor(Ls[i], m, 64);
        }
    if (l16 == 0) {
        #pragma unroll
        for (int r = 0; r < 4; ++r) {
            const int row = ri + 4 * q + r;
            EpP[jb * NB + row] = Ep[r];   // plain stores, unique writer
            EnP[jb * NB + row] = En[r];
            LsP[jb * NB + row] = Ls[r];
        }
    }

    // ---- 16th block to finish this i-block reduces its 128 rows ----
    __shared__ int lastFlag;
    __shared__ float wsum[8];
    __threadfence();                           // release this block's stores
    __syncthreads();
    if (threadIdx.x == 0)
        lastFlag = (atomicAdd(&ctr[ib], 1) == JS - 1) ? 1 : 0;
    __syncthreads();
    if (!lastFlag) return;
    __threadfence();                           // acquire other blocks' stores

    const int tid = threadIdx.x;
    int tot[4] = {0, 0, 0, 0};
    #pragma unroll
    for (int hh = 0; hh < NH; ++hh)
        #pragma unroll
        for (int cc = 0; cc < 4; ++cc) tot[cc] += cntP[hh * 4 + cc];
    float contrib = 0.0f;
    if (tid < 128) {
        const int row = ib * 128 + tid;
        float ep = 0.f, en = 0.f, ls = 0.f;
        #pragma unroll
        for (int jb2 = 0; jb2 < JS; ++jb2) {
            ep += __hip_atomic_load(&EpP[jb2 * NB + row], __ATOMIC_RELAXED, __HIP_MEMORY_SCOPE_AGENT);
            en += __hip_atomic_load(&EnP[jb2 * NB + row], __ATOMIC_RELAXED, __HIP_MEMORY_SCOPE_AGENT);
            ls += __hip_atomic_load(&LsP[jb2 * NB + row], __ATOMIC_RELAXED, __HIP_MEMORY_SCOPE_AGENT);
        }
        const int c = clsS[row];
        const int pc = c ^ 1, nc = c ^ 2;
        const int pcnt = (pc == 0) ? tot[0] : (pc == 1) ? tot[1] : (pc == 2) ? tot[2] : tot[3];
        const int ncnt = (nc == 0) ? tot[0] : (nc == 1) ? tot[1] : (nc == 2) ? tot[2] : tot[3];
        if (pcnt > 0 && ncnt > 0) {
            const float ld = logf(ep + en);
            contrib = -(TEMP_INV * ls - (float)pcnt * ld) / ((float)pcnt * (float)NB);
        }
    }
    #pragma unroll
    for (int m = 1; m < 64; m <<= 1) contrib += __shfl_xor(contrib, m, 64);
    if ((tid & 63) == 0) wsum[tid >> 6] = contrib;
    __syncthreads();
    if (tid == 0) {
        float s = 0.f;
        #pragma unroll
        for (int w = 0; w < 8; ++w) s += wsum[w];
        atomicAdd(out, s);
    }
}

extern "C" void kernel_launch(void* const* d_in, const int* in_sizes, int n_in,
                              void* d_out, int out_size, void* d_ws, size_t ws_size,
                              hipStream_t stream) {
    const float* F = (const float*)d_in[0];
    const int* dix = (const int*)d_in[1];
    const int* tt  = (const int*)d_in[2];
    const int* tp  = (const int*)d_in[3];
    float* out = (float*)d_out;

    char* ws = (char*)d_ws;
    unsigned short* G   = (unsigned short*)(ws + OFF_G);
    unsigned char* clsS = (unsigned char*)(ws + OFF_CLS);
    int* cntP           = (int*)(ws + OFF_CNT);
    int* ctr            = (int*)(ws + OFF_CTR);
    float* EpP          = (float*)(ws + OFF_EPP);
    float* EnP          = (float*)(ws + OFF_ENP);
    float* LsP          = (float*)(ws + OFF_LSP);
    unsigned char* clsO = (unsigned char*)(ws + OFF_CO);   // aliases EpP (dead
    unsigned short* rl  = (unsigned short*)(ws + OFF_RL);  //  before sim writes)

    classify_kernel<<<NH, 1024, 0, stream>>>(dix, tt, tp, clsO, rl, cntP, ctr, out);
    normscatter_kernel<<<2048, 256, 0, stream>>>(F, clsO, rl, cntP, G, clsS);
    sim_kernel<<<NIB * JS, 512, 0, stream>>>(G, clsS, cntP, ctr, EpP, EnP, LsP, out);
}

// Round 16
// 101.895 us; speedup vs baseline: 2.3199x; 2.3199x over previous
//
#include <hip/hip_runtime.h>

// ContrastiveLoss: B=8192, D=128, T=0.1, SINGLE_POS=False.
// Classes c = 2*tt + tp in {0..3}; pos class = c^1, neg class = c^2.
// Rows counting-sorted by class; each wave visits only the <=2 relevant
// column segments. B staged per 64-row panel via global_load_lds, double
// buffer, rotation swizzle (verified absmax 0.0 lineage).
// 8 waves x 16 rows (512-thr blocks) — fits the empirically-immovable
// 64-VGPR allocation; 4 blocks/CU x 8 waves = 32 waves/CU.
// [Verbatim revert to the 101.98-us r13 kernel: r14's finalize-fold
//  (all-thread __threadfence + arrival counters) quintupled sim.]

#define NB 8192
#define ND 128
#define NIB 64          // i-blocks (128 rows each)
#define JS 16           // j-slices -> grid 64*16 = 1024 blocks (4/CU @ 32KB LDS)
#define NH 8            // classify histogram groups (1024 rows each)
#define TEMP_INV 10.0f
#define LOG2E 1.4426950408889634f
#define EXPK (TEMP_INV * LOG2E)

typedef __attribute__((ext_vector_type(8))) short short8;
typedef __attribute__((ext_vector_type(4))) float f32x4;

// ws layout (bytes)
#define OFF_G    0                         // 8192*128 bf16 = 2 MB
#define OFF_CLS  (NB * ND * 2)             // sorted classes u8[8192]
#define OFF_CNT  (OFF_CLS + NB)            // per-h class hist int[NH*4]
#define OFF_EPP  (OFF_CNT + 128)           // JS*8192 f32 partials
#define OFF_ENP  (OFF_EPP + NB * 4 * JS)
#define OFF_LSP  (OFF_ENP + NB * 4 * JS)
// aliased into the Ep partial region (dead before sim overwrites every slot):
#define OFF_CO   OFF_EPP                   // original classes u8[8192]
#define OFF_RL   (OFF_EPP + NB)            // local rank in (h,class) u16[8192]

__device__ __forceinline__ unsigned short f2bf(float x) {
    unsigned int u = __float_as_uint(x);
    unsigned int r = (u + 0x7FFFu + ((u >> 16) & 1u)) >> 16;  // RNE
    return (unsigned short)r;
}

__device__ __forceinline__ float fast_exp2(float x) {
#if __has_builtin(__builtin_amdgcn_exp2f)
    return __builtin_amdgcn_exp2f(x);
#else
    return exp2f(x);
#endif
}

typedef const __attribute__((address_space(1))) void gas_void;
typedef __attribute__((address_space(3))) void las_void;
__device__ __forceinline__ void gload_lds16(const void* g, void* s) {
    // width-16 global->LDS DMA; LDS dest = uniform base + lane*16 (HW rule)
    __builtin_amdgcn_global_load_lds((gas_void*)g, (las_void*)s, 16, 0, 0);
}

// 8 blocks x 1024 (1 row/thread): classes, per-(h,class) hist + local ranks.
__global__ __launch_bounds__(1024) void classify_kernel(
    const int* __restrict__ dix, const int* __restrict__ tt, const int* __restrict__ tp,
    unsigned char* __restrict__ clsO, unsigned short* __restrict__ rlocal,
    int* __restrict__ cntP, float* __restrict__ out)
{
    __shared__ int lh[4];
    const int h = blockIdx.x, tid = threadIdx.x;
    if (tid < 4) lh[tid] = 0;
    __syncthreads();
    const int row = h * 1024 + tid;
    const int ix  = dix[row];
    const int c   = ((tt[ix] & 1) << 1) | (tp[ix] & 1);
    clsO[row] = (unsigned char)c;
    rlocal[row] = (unsigned short)atomicAdd(&lh[c], 1);
    if (h == 0 && tid == 0) *out = 0.0f;
    __syncthreads();
    if (tid < 4) cntP[h * 4 + tid] = lh[tid];
}

// 2048 blocks x 256 (wave per row): normalize row, scatter to sorted slot.
__global__ __launch_bounds__(256) void normscatter_kernel(
    const float* __restrict__ F, const unsigned char* __restrict__ clsO,
    const unsigned short* __restrict__ rlocal, const int* __restrict__ cntP,
    unsigned short* __restrict__ G, unsigned char* __restrict__ clsS)
{
    const int row  = blockIdx.x * 4 + (threadIdx.x >> 6);
    const int lane = threadIdx.x & 63;
    const int c = clsO[row];
    const int h = row >> 10;                 // 1024 rows per hist group
    int base = (int)rlocal[row];
    #pragma unroll
    for (int cc = 0; cc < 3; ++cc)           // classes below c (wave-uniform)
        if (cc < c) {
            #pragma unroll
            for (int hh = 0; hh < NH; ++hh) base += cntP[hh * 4 + cc];
        }
    #pragma unroll
    for (int hh = 0; hh < NH - 1; ++hh)      // earlier hist groups, same class
        if (hh < h) base += cntP[hh * 4 + c];

    const float2 v = *(const float2*)(F + row * ND + lane * 2);
    float ss = v.x * v.x + v.y * v.y;
    #pragma unroll
    for (int m = 1; m < 64; m <<= 1) ss += __shfl_xor(ss, m, 64);
    const float inv = rsqrtf(fmaxf(ss, 1e-24f));
    ushort2 st; st.x = f2bf(v.x * inv); st.y = f2bf(v.y * inv);
    *(ushort2*)(G + base * ND + lane * 2) = st;
    if (lane == 0) clsS[base] = (unsigned char)c;
}

// Stage one 64-row panel with 8 waves: wave wu stages rows wu*8..wu*8+7
// (2 gload_lds per wave). Lane l -> row pr = wu*8 + j*4 + (l>>4); slot l&15
// holds global chunk (slot - pr) & 15 (rotation; read applies same perm).
__device__ __forceinline__ void stage_panel(
    const unsigned short* __restrict__ G, unsigned short* Blds,
    int rbase, int wu, int lrow4, int lpos)
{
    #pragma unroll
    for (int j = 0; j < 2; ++j) {
        const int pr = wu * 8 + j * 4 + lrow4;
        int rowG = rbase + pr;
        rowG = (rowG < NB - 1) ? rowG : (NB - 1);   // clamp (masked in compute)
        const int chunk = (lpos - pr) & 15;
        gload_lds16(G + rowG * ND + chunk * 8, Blds + (wu * 8 + j * 4) * ND);
    }
}

// MODE: 0 = stage-only (inactive wave), 1 = POS (Ep,Ls), 2 = NEG (En),
// 3 = weighted both (straddling waves only — rare after sorting).
// Double-buffered 2-phase: stage(p+1) issued BEFORE compute(p).
template<int MODE>
__device__ __forceinline__ void seg_panels(
    const unsigned short* __restrict__ G, unsigned short* Blds0,
    unsigned short* Blds1, const short8 (&A)[4],
    float (&Ep)[4], float (&En)[4], float (&Ls)[4],
    const float (&wp)[4], const float (&wn)[4],
    int cs, int ce, int p0, int p1, int wu, int lane)
{
    const int lrow4 = lane >> 4, lpos = lane & 15;
    const int q = lane >> 4, l16 = lane & 15;

    stage_panel(G, Blds0, cs + p0 * 64, wu, lrow4, lpos);
    __syncthreads();                       // panel p0 ready
    #pragma unroll 1
    for (int p = p0; p < p1; ++p) {
        const int cur = (p - p0) & 1;
        unsigned short* bufC = cur ? Blds1 : Blds0;
        if (p + 1 < p1)                    // prefetch next panel into other buf
            stage_panel(G, cur ? Blds0 : Blds1, cs + (p + 1) * 64, wu, lrow4, lpos);
        if (MODE != 0) {
            #pragma unroll
            for (int st = 0; st < 4; ++st) {
                const int j0 = cs + p * 64 + st * 16;
                if (j0 >= ce) break;       // wave-uniform tail cutoff
                short8 Bf[4];
                #pragma unroll
                for (int c = 0; c < 4; ++c) {
                    const int slot = (c * 4 + q + l16) & 15;    // rotation
                    Bf[c] = *(const short8*)&bufC[(st * 16 + l16) * ND + slot * 8];
                }
                f32x4 acc = {0.f, 0.f, 0.f, 0.f};
                #pragma unroll
                for (int c = 0; c < 4; ++c)
                    acc = __builtin_amdgcn_mfma_f32_16x16x32_bf16(A[c], Bf[c], acc, 0, 0, 0);
                if (j0 + 16 <= ce) {       // full subtile
                    #pragma unroll
                    for (int r = 0; r < 4; ++r) {
                        const float sv = acc[r];
                        const float e  = fast_exp2(sv * EXPK);
                        if (MODE == 1)      { Ep[r] += e; Ls[r] += sv; }
                        else if (MODE == 2) { En[r] += e; }
                        else {
                            Ep[r] = fmaf(wp[r], e,  Ep[r]);
                            Ls[r] = fmaf(wp[r], sv, Ls[r]);
                            En[r] = fmaf(wn[r], e,  En[r]);
                        }
                    }
                } else {                   // masked tail subtile
                    const float vm = ((j0 + l16) < ce) ? 1.f : 0.f;
                    #pragma unroll
                    for (int r = 0; r < 4; ++r) {
                        const float sv = acc[r] * vm;
                        const float e  = fast_exp2(sv * EXPK) * vm;
                        if (MODE == 1)      { Ep[r] += e; Ls[r] += sv; }
                        else if (MODE == 2) { En[r] += e; }
                        else {
                            Ep[r] = fmaf(wp[r], e,  Ep[r]);
                            Ls[r] = fmaf(wp[r], sv, Ls[r]);
                            En[r] = fmaf(wn[r], e,  En[r]);
                        }
                    }
                }
            }
        }
        __syncthreads();   // drains prefetch vmcnt + fences reads of bufC
    }
}

// Grid 64 i-blocks x 16 j-slices = 1024 blocks of 512 threads (8 waves).
// Wave owns 16 sorted rows (fits the 64-VGPR clamp); 4 blocks/CU resident.
__global__ __launch_bounds__(512) void sim_kernel(
    const unsigned short* __restrict__ G, const unsigned char* __restrict__ clsS,
    const int* __restrict__ cntP,
    float* __restrict__ EpP, float* __restrict__ EnP, float* __restrict__ LsP)
{
    __shared__ unsigned short Blds[2][64 * 128];   // 2 x 16 KB

    const int ib = blockIdx.x & (NIB - 1);
    const int jb = blockIdx.x >> 6;          // 0..JS-1
    const int wave = threadIdx.x >> 6, lane = threadIdx.x & 63;
    const int q = lane >> 4, l16 = lane & 15;
    const int ri = ib * 128 + wave * 16;     // this wave's 16 rows
    const int wu = __builtin_amdgcn_readfirstlane(wave);

    short8 A[4];
    #pragma unroll
    for (int c = 0; c < 4; ++c)
        A[c] = *(const short8*)(G + (ri + l16) * ND + c * 32 + q * 8);

    // this lane's 4 output-row classes (C/D row = 4q + r)
    const unsigned int rc = *(const unsigned int*)(clsS + ri + 4 * q);
    const int wF = clsS[ri], wL = clsS[ri + 15];              // wave class range
    const int bF = clsS[ib * 128], bL = clsS[ib * 128 + 127]; // block class range

    float Ep[4], En[4], Ls[4];
    #pragma unroll
    for (int i = 0; i < 4; ++i) { Ep[i] = 0.f; En[i] = 0.f; Ls[i] = 0.f; }
    float wp[4], wn[4];   // written only on the (rare) straddle path

    int cs = 0;
    #pragma unroll 1
    for (int s = 0; s < 4; ++s) {
        int len = 0;
        #pragma unroll
        for (int h = 0; h < NH; ++h) len += cntP[h * 4 + s];
        const int ce = cs + len;
        const int s1 = s ^ 1, s2 = s ^ 2;
        const bool aPb = (s1 >= bF) && (s1 <= bL);   // block-uniform activity
        const bool aNb = (s2 >= bF) && (s2 <= bL);
        if (aPb || aNb) {
            const int np = (len + 63) >> 6;          // 64-row panels
            const int p0 = (jb * np) >> 4;           // this block's panel range
            const int p1 = ((jb + 1) * np) >> 4;
            if (p0 < p1) {
                if (wF == wL) {                       // pure-class wave (common)
                    if (s1 == wF)
                        seg_panels<1>(G, Blds[0], Blds[1], A, Ep, En, Ls, wp, wn, cs, ce, p0, p1, wu, lane);
                    else if (s2 == wF)
                        seg_panels<2>(G, Blds[0], Blds[1], A, Ep, En, Ls, wp, wn, cs, ce, p0, p1, wu, lane);
                    else
                        seg_panels<0>(G, Blds[0], Blds[1], A, Ep, En, Ls, wp, wn, cs, ce, p0, p1, wu, lane);
                } else {                              // straddling wave (rare)
                    #pragma unroll
                    for (int r = 0; r < 4; ++r) {
                        const int cr = (rc >> (8 * r)) & 0xff;
                        wp[r] = (cr == s1) ? 1.f : 0.f;
                        wn[r] = (cr == s2) ? 1.f : 0.f;
                    }
                    seg_panels<3>(G, Blds[0], Blds[1], A, Ep, En, Ls, wp, wn, cs, ce, p0, p1, wu, lane);
                }
            }
        }
        cs = ce;
    }

    // reduce across the 16 column-lanes
    #pragma unroll
    for (int m = 1; m < 16; m <<= 1)
        #pragma unroll
        for (int i = 0; i < 4; ++i) {
            Ep[i] += __shfl_xor(Ep[i], m, 64);
            En[i] += __shfl_xor(En[i], m, 64);
            Ls[i] += __shfl_xor(Ls[i], m, 64);
        }
    if (l16 == 0) {
        #pragma unroll
        for (int r = 0; r < 4; ++r) {
            const int row = ri + 4 * q + r;
            EpP[jb * NB + row] = Ep[r];   // plain stores, unique writer
            EnP[jb * NB + row] = En[r];
            LsP[jb * NB + row] = Ls[r];
        }
    }
}

__global__ __launch_bounds__(256) void finalize_kernel(
    const float* __restrict__ EpP, const float* __restrict__ EnP,
    const float* __restrict__ LsP, const unsigned char* __restrict__ clsS,
    const int* __restrict__ cntP, float* __restrict__ out)
{
    const int i = blockIdx.x * 256 + threadIdx.x;
    int tot[4] = {0, 0, 0, 0};
    #pragma unroll
    for (int hh = 0; hh < NH; ++hh)
        #pragma unroll
        for (int cc = 0; cc < 4; ++cc) tot[cc] += cntP[hh * 4 + cc];
    const int c = clsS[i];
    const int pc = c ^ 1, nc = c ^ 2;
    const int pcnt = (pc == 0) ? tot[0] : (pc == 1) ? tot[1] : (pc == 2) ? tot[2] : tot[3];
    const int ncnt = (nc == 0) ? tot[0] : (nc == 1) ? tot[1] : (nc == 2) ? tot[2] : tot[3];
    float ep = 0.f, en = 0.f, ls = 0.f;
    #pragma unroll
    for (int jb = 0; jb < JS; ++jb) {
        ep += EpP[jb * NB + i];
        en += EnP[jb * NB + i];
        ls += LsP[jb * NB + i];
    }
    float contrib = 0.0f;
    if (pcnt > 0 && ncnt > 0) {
        const float ld = logf(ep + en);
        contrib = -(TEMP_INV * ls - (float)pcnt * ld) / ((float)pcnt * (float)NB);
    }
    #pragma unroll
    for (int m = 1; m < 64; m <<= 1) contrib += __shfl_xor(contrib, m, 64);
    __shared__ float wsum[4];
    if ((threadIdx.x & 63) == 0) wsum[threadIdx.x >> 6] = contrib;
    __syncthreads();
    if (threadIdx.x == 0)
        atomicAdd(out, wsum[0] + wsum[1] + wsum[2] + wsum[3]);
}

extern "C" void kernel_launch(void* const* d_in, const int* in_sizes, int n_in,
                              void* d_out, int out_size, void* d_ws, size_t ws_size,
                              hipStream_t stream) {
    const float* F = (const float*)d_in[0];
    const int* dix = (const int*)d_in[1];
    const int* tt  = (const int*)d_in[2];
    const int* tp  = (const int*)d_in[3];
    float* out = (float*)d_out;

    char* ws = (char*)d_ws;
    unsigned short* G   = (unsigned short*)(ws + OFF_G);
    unsigned char* clsS = (unsigned char*)(ws + OFF_CLS);
    int* cntP           = (int*)(ws + OFF_CNT);
    float* EpP          = (float*)(ws + OFF_EPP);
    float* EnP          = (float*)(ws + OFF_ENP);
    float* LsP          = (float*)(ws + OFF_LSP);
    unsigned char* clsO = (unsigned char*)(ws + OFF_CO);   // aliases EpP (dead
    unsigned short* rl  = (unsigned short*)(ws + OFF_RL);  //  before sim writes)

    classify_kernel<<<NH, 1024, 0, stream>>>(dix, tt, tp, clsO, rl, cntP, out);
    normscatter_kernel<<<2048, 256, 0, stream>>>(F, clsO, rl, cntP, G, clsS);
    sim_kernel<<<NIB * JS, 512, 0, stream>>>(G, clsS, cntP, EpP, EnP, LsP);
    finalize_kernel<<<NB / 256, 256, 0, stream>>>(EpP, EnP, LsP, clsS, cntP, out);
}